// Round 1
// baseline (728.063 us; speedup 1.0000x reference)
//
#include <hip/hip_runtime.h>
#include <cstdint>
#include <cstddef>

// ---------------------------------------------------------------------------
// GCN forward on MI355X.
// R5: rebalance the fused count+gemm kernel. Previous mix (4 count blocks :
//     1 gemm block, 1 edge/thread) starved the GEMM role: 25.6KB LDS caps
//     residency at 6 blocks/CU and 80% of those slots were count blocks
//     idling on a single atomic round-trip. Now: count role does 8
//     edges/thread (loads batched ahead of 16 independent atomics), count
//     blocks 6252 -> 782, mix 1 count : 2 gemm. GEMM residency ~4 blocks/CU.
// ---------------------------------------------------------------------------

#define R_REP 8
#define EPT 8  // edges per count-role thread

static __device__ __forceinline__ float4 ld4(const float* p) { return *(const float4*)p; }

static __device__ __forceinline__ float bf2f(unsigned int u) {
  union { unsigned int i; float f; } x; x.i = u << 16; return x.f;
}
static __device__ __forceinline__ unsigned int f2bf(float f) {
  union { float f; unsigned int i; } x; x.f = f;
  unsigned int r = x.i + 0x7fff + ((x.i >> 16) & 1);  // RTN-even
  return r >> 16;
}

// ---- fused: count role (1 of 3 blocks) + layer-0 gemm role (2 of 3) -------
// count: cnt[dst*8+(e&7)] returning atomic -> pos[e]; dego replicas.
//        8 edges/thread: all loads issued first, then 16 independent atomics.
// gemm:  t0b[n,128](bf16) = x[n,256] @ W0[256,128]  (fp32 accum, NO scale)
__global__ __launch_bounds__(256, 6) void fused_count_gemm(
    const int* __restrict__ src, const int* __restrict__ dst,
    int* __restrict__ cnt, int* __restrict__ dego, uint8_t* __restrict__ pos,
    const float* __restrict__ x, const float* __restrict__ W0,
    ushort* __restrict__ t0b, int n, int E, int ngemm, int ncnt) {
  __shared__ float As[64][36];
  __shared__ float Bs[32][128];
  int b = blockIdx.x;
  int g = b / 3, r3 = b - g * 3;
  if (r3 == 0) {  // ---- count role: chunk g of 2048 edges ----
    if (g >= ncnt) return;
    int base = g * (256 * EPT) + threadIdx.x;
    int sa[EPT], da[EPT];
    bool va[EPT];
#pragma unroll
    for (int j = 0; j < EPT; j++) {
      int e = base + j * 256;
      va[j] = (e < E);
      sa[j] = va[j] ? src[e] : 0;
      da[j] = va[j] ? dst[e] : 0;
    }
#pragma unroll
    for (int j = 0; j < EPT; j++) {
      if (va[j]) {
        int e = base + j * 256;
        int rep = e & (R_REP - 1);
        int p = atomicAdd(&cnt[(size_t)da[j] * R_REP + rep], 1);
        pos[e] = (uint8_t)p;
        atomicAdd(&dego[(size_t)rep * n + sa[j]], 1);
      }
    }
    return;
  }
  // ---- gemm role: tile g*2 + (r3-1) ----
  int tile = g * 2 + (r3 - 1);
  if (tile >= ngemm) return;
  int tid = threadIdx.x;
  int tx = tid & 15;
  int ty = tid >> 4;
  int row0 = tile * 64;
  float acc[4][8];
#pragma unroll
  for (int i = 0; i < 4; i++)
#pragma unroll
    for (int j = 0; j < 8; j++) acc[i][j] = 0.0f;

  for (int kt = 0; kt < 256; kt += 32) {
#pragma unroll
    for (int l = 0; l < 2; l++) {
      int idx = tid + l * 256;
      int m = idx >> 3, q = idx & 7;
      int gr = row0 + m;
      float4 v = make_float4(0.f, 0.f, 0.f, 0.f);
      if (gr < n) v = ld4(&x[(size_t)gr * 256 + kt + q * 4]);
      *(float4*)&As[m][q * 4] = v;
    }
#pragma unroll
    for (int l = 0; l < 4; l++) {
      int idx = tid + l * 256;
      int kk = idx >> 5, q = idx & 31;
      *(float4*)&Bs[kk][q * 4] = ld4(&W0[(size_t)(kt + kk) * 128 + q * 4]);
    }
    __syncthreads();
#pragma unroll
    for (int k = 0; k < 32; k++) {
      float a[4];
#pragma unroll
      for (int i = 0; i < 4; i++) a[i] = As[ty * 4 + i][k];
      float4 b0 = *(float4*)&Bs[k][tx * 8];
      float4 b1 = *(float4*)&Bs[k][tx * 8 + 4];
      float bb[8] = {b0.x, b0.y, b0.z, b0.w, b1.x, b1.y, b1.z, b1.w};
#pragma unroll
      for (int i = 0; i < 4; i++)
#pragma unroll
        for (int j = 0; j < 8; j++) acc[i][j] = fmaf(a[i], bb[j], acc[i][j]);
    }
    __syncthreads();
  }
#pragma unroll
  for (int i = 0; i < 4; i++) {
    int r = row0 + ty * 4 + i;
    if (r < n) {
      uint4 o;
      o.x = f2bf(acc[i][0]) | (f2bf(acc[i][1]) << 16);
      o.y = f2bf(acc[i][2]) | (f2bf(acc[i][3]) << 16);
      o.z = f2bf(acc[i][4]) | (f2bf(acc[i][5]) << 16);
      o.w = f2bf(acc[i][6]) | (f2bf(acc[i][7]) << 16);
      *(uint4*)&t0b[(size_t)r * 128 + tx * 8] = o;
    }
  }
}

// c_src from summed out-degree replicas.
__global__ void norm_kernel(const int* __restrict__ dego, float* __restrict__ c_src, int n) {
  int i = blockIdx.x * blockDim.x + threadIdx.x;
  if (i < n) {
    int s = 0;
#pragma unroll
    for (int r = 0; r < R_REP; r++) s += dego[(size_t)r * n + i];
    c_src[i] = rsqrtf(fmaxf((float)s, 1.0f));
  }
}

// --- multi-block exclusive scan over nbins = n*R_REP (1024 elems/block) ----
__global__ __launch_bounds__(256) void scan_partial(const int* __restrict__ v,
                                                    int* __restrict__ partials, int nbins) {
  __shared__ int lds[256];
  int base = blockIdx.x * 1024 + threadIdx.x * 4;
  int s = 0;
#pragma unroll
  for (int j = 0; j < 4; j++) s += (base + j < nbins) ? v[base + j] : 0;
  lds[threadIdx.x] = s;
  __syncthreads();
#pragma unroll
  for (int off = 128; off > 0; off >>= 1) {
    if (threadIdx.x < off) lds[threadIdx.x] += lds[threadIdx.x + off];
    __syncthreads();
  }
  if (threadIdx.x == 0) partials[blockIdx.x] = lds[0];
}

__global__ __launch_bounds__(1024) void scan_blocksums(int* __restrict__ partials, int nb) {
  __shared__ int lds[1024];
  int t = threadIdx.x;
  int v = (t < nb) ? partials[t] : 0;
  lds[t] = v;
  __syncthreads();
#pragma unroll
  for (int off = 1; off < 1024; off <<= 1) {
    int u = (t >= off) ? lds[t - off] : 0;
    __syncthreads();
    lds[t] += u;
    __syncthreads();
  }
  if (t < nb) partials[t] = lds[t] - v;  // exclusive
}

__global__ __launch_bounds__(256) void scan_final(const int* __restrict__ v,
                                                  const int* __restrict__ partials,
                                                  int* __restrict__ row_start, int nbins) {
  __shared__ int lds[256];
  int base = blockIdx.x * 1024 + threadIdx.x * 4;
  int e[4];
  int s = 0;
#pragma unroll
  for (int j = 0; j < 4; j++) {
    e[j] = (base + j < nbins) ? v[base + j] : 0;
    s += e[j];
  }
  lds[threadIdx.x] = s;
  __syncthreads();
#pragma unroll
  for (int off = 1; off < 256; off <<= 1) {
    int u = (threadIdx.x >= off) ? lds[threadIdx.x - off] : 0;
    __syncthreads();
    lds[threadIdx.x] += u;
    __syncthreads();
  }
  int run = lds[threadIdx.x] - s + partials[blockIdx.x];
#pragma unroll
  for (int j = 0; j < 4; j++) {
    if (base + j < nbins) row_start[base + j] = run;
    run += e[j];
    if (base + j == nbins - 1) row_start[nbins] = run;
  }
}

// atomic-free scatter
__global__ void fill_csr(const int* __restrict__ src, const int* __restrict__ dst,
                         const int* __restrict__ row_start, const uint8_t* __restrict__ pos,
                         int* __restrict__ csr_src, int E) {
  int e = blockIdx.x * blockDim.x + threadIdx.x;
  if (e < E) {
    int bin = dst[e] * R_REP + (e & (R_REP - 1));
    csr_src[row_start[bin] + (int)pos[e]] = src[e];
  }
}

// t1b[n,128](bf16) = (h1b[n,128](bf16) @ W1[128,128]) * c_src[n]  (fp32 accum)
__global__ __launch_bounds__(256) void gemm128_bf16(const ushort* __restrict__ A,
                                                    const float* __restrict__ W,
                                                    const float* __restrict__ c,
                                                    ushort* __restrict__ Y, int n) {
  __shared__ float As[64][36];
  __shared__ float Bs[32][128];
  int tid = threadIdx.x;
  int tx = tid & 15;
  int ty = tid >> 4;
  int row0 = blockIdx.x * 64;
  float acc[4][8];
#pragma unroll
  for (int i = 0; i < 4; i++)
#pragma unroll
    for (int j = 0; j < 8; j++) acc[i][j] = 0.0f;

  for (int kt = 0; kt < 128; kt += 32) {
    {  // stage A: 64 rows x 32 bf16 -> float; 8 elems/thread
      int m = tid >> 2, q = tid & 3;
      int gr = row0 + m;
      uint4 w = make_uint4(0u, 0u, 0u, 0u);
      if (gr < n) w = *(const uint4*)&A[(size_t)gr * 128 + kt + q * 8];
      float4 f0 = make_float4(bf2f(w.x & 0xffff), bf2f(w.x >> 16),
                              bf2f(w.y & 0xffff), bf2f(w.y >> 16));
      float4 f1 = make_float4(bf2f(w.z & 0xffff), bf2f(w.z >> 16),
                              bf2f(w.w & 0xffff), bf2f(w.w >> 16));
      *(float4*)&As[m][q * 8] = f0;
      *(float4*)&As[m][q * 8 + 4] = f1;
    }
#pragma unroll
    for (int l = 0; l < 4; l++) {
      int idx = tid + l * 256;
      int kk = idx >> 5, q = idx & 31;
      *(float4*)&Bs[kk][q * 4] = ld4(&W[(size_t)(kt + kk) * 128 + q * 4]);
    }
    __syncthreads();
#pragma unroll
    for (int k = 0; k < 32; k++) {
      float a[4];
#pragma unroll
      for (int i = 0; i < 4; i++) a[i] = As[ty * 4 + i][k];
      float4 b0 = *(float4*)&Bs[k][tx * 8];
      float4 b1 = *(float4*)&Bs[k][tx * 8 + 4];
      float bb[8] = {b0.x, b0.y, b0.z, b0.w, b1.x, b1.y, b1.z, b1.w};
#pragma unroll
      for (int i = 0; i < 4; i++)
#pragma unroll
        for (int j = 0; j < 8; j++) acc[i][j] = fmaf(a[i], bb[j], acc[i][j]);
    }
    __syncthreads();
  }
#pragma unroll
  for (int i = 0; i < 4; i++) {
    int r = row0 + ty * 4 + i;
    if (r < n) {
      float s = c[r];
      uint4 o;
      o.x = f2bf(acc[i][0] * s) | (f2bf(acc[i][1] * s) << 16);
      o.y = f2bf(acc[i][2] * s) | (f2bf(acc[i][3] * s) << 16);
      o.z = f2bf(acc[i][4] * s) | (f2bf(acc[i][5] * s) << 16);
      o.w = f2bf(acc[i][6] * s) | (f2bf(acc[i][7] * s) << 16);
      *(uint4*)&Y[(size_t)r * 128 + tx * 8] = o;
    }
  }
}

// One wave per dst node; lane holds 2 bf16 features (4B load per edge).
// SCALE: multiply each gathered row by c_src[s].  OUT_BF16: write bf16 pair.
template <bool RELU, bool SCALE, bool OUT_BF16>
__global__ __launch_bounds__(256) void agg_kernel(const ushort* __restrict__ T,
                                                  const int* __restrict__ row_start,
                                                  const int* __restrict__ csr_src,
                                                  const float* __restrict__ c_src,
                                                  const float* __restrict__ bias,
                                                  void* __restrict__ out, int n) {
  int node = (blockIdx.x * 256 + threadIdx.x) >> 6;
  int lane = threadIdx.x & 63;
  if (node >= n) return;
  int e0 = row_start[node * R_REP], e1 = row_start[node * R_REP + R_REP];
  float ax = 0.f, ay = 0.f;
  int e = e0;
  for (; e + 1 < e1; e += 2) {  // 2-wide: two gathers in flight
    int s0 = csr_src[e], s1 = csr_src[e + 1];
    unsigned int w0 = *(const unsigned int*)&T[(size_t)s0 * 128 + lane * 2];
    unsigned int w1 = *(const unsigned int*)&T[(size_t)s1 * 128 + lane * 2];
    float fx0 = bf2f(w0 & 0xffff), fy0 = bf2f(w0 >> 16);
    float fx1 = bf2f(w1 & 0xffff), fy1 = bf2f(w1 >> 16);
    if (SCALE) {
      float cs0 = c_src[s0], cs1 = c_src[s1];
      fx0 *= cs0; fy0 *= cs0; fx1 *= cs1; fy1 *= cs1;
    }
    ax += fx0 + fx1;
    ay += fy0 + fy1;
  }
  if (e < e1) {
    int s0 = csr_src[e];
    unsigned int w0 = *(const unsigned int*)&T[(size_t)s0 * 128 + lane * 2];
    float fx0 = bf2f(w0 & 0xffff), fy0 = bf2f(w0 >> 16);
    if (SCALE) { float cs0 = c_src[s0]; fx0 *= cs0; fy0 *= cs0; }
    ax += fx0;
    ay += fy0;
  }
  float cd = rsqrtf(fmaxf((float)(e1 - e0), 1.0f));
  float rx = fmaf(ax, cd, bias[lane * 2]);
  float ry = fmaf(ay, cd, bias[lane * 2 + 1]);
  if (RELU) { rx = fmaxf(rx, 0.f); ry = fmaxf(ry, 0.f); }
  if (OUT_BF16) {
    ((unsigned int*)out)[(size_t)node * 64 + lane] = f2bf(rx) | (f2bf(ry) << 16);
  } else {
    float2 r2; r2.x = rx; r2.y = ry;
    ((float2*)out)[(size_t)node * 64 + lane] = r2;
  }
}

// logits[n,40] = relu(H[n,128]) @ Wc[128,40] + bc
__global__ __launch_bounds__(256) void logits_kernel(const float* __restrict__ H,
                                                     const float* __restrict__ Wc,
                                                     const float* __restrict__ bc,
                                                     float* __restrict__ out, int n) {
  __shared__ float Wl[128 * 40];
  for (int i = threadIdx.x; i < 128 * 40; i += 256) Wl[i] = Wc[i];
  __syncthreads();
  int rl = threadIdx.x >> 3;
  int cg = threadIdx.x & 7;
  int r = blockIdx.x * 32 + rl;
  if (r >= n) return;
  float acc[5] = {0.f, 0.f, 0.f, 0.f, 0.f};
  const float* hr = &H[(size_t)r * 128];
  for (int k = 0; k < 128; k++) {
    float v = fmaxf(hr[k], 0.f);
#pragma unroll
    for (int j = 0; j < 5; j++) acc[j] = fmaf(v, Wl[k * 40 + cg * 5 + j], acc[j]);
  }
#pragma unroll
  for (int j = 0; j < 5; j++) out[(size_t)r * 40 + cg * 5 + j] = acc[j] + bc[cg * 5 + j];
}

extern "C" void kernel_launch(void* const* d_in, const int* in_sizes, int n_in,
                              void* d_out, int out_size, void* d_ws, size_t ws_size,
                              hipStream_t stream) {
  const float* x = (const float*)d_in[0];
  const int* src = (const int*)d_in[1];
  const int* dst = (const int*)d_in[2];
  const float* W0 = (const float*)d_in[3];
  const float* b0 = (const float*)d_in[4];
  const float* W1 = (const float*)d_in[5];
  const float* b1 = (const float*)d_in[6];
  const float* Wc = (const float*)d_in[7];
  const float* bc = (const float*)d_in[8];
  const int n = in_sizes[0] / 256;
  const int E = in_sizes[1];
  const int nbins = n * R_REP;

  char* wsp = (char*)d_ws;
  auto alloc = [&](size_t bytes) -> char* {
    char* p = wsp;
    wsp += (bytes + 255) & ~(size_t)255;
    return p;
  };
  ushort* t0b = (ushort*)alloc((size_t)n * 128 * sizeof(ushort));  // t0 / reused as t1
  ushort* h1b = (ushort*)alloc((size_t)n * 128 * sizeof(ushort));
  float* c_src = (float*)alloc((size_t)n * sizeof(float));
  int* zeroed = (int*)alloc((size_t)(nbins + R_REP * n) * sizeof(int));  // cnt | dego
  int* cnt = zeroed;
  int* dego = zeroed + nbins;
  int* row_start = (int*)alloc((size_t)(nbins + 1) * sizeof(int));
  int* partials = (int*)alloc((size_t)1024 * sizeof(int));
  uint8_t* pos = (uint8_t*)alloc((size_t)E);
  int* csr = (int*)alloc((size_t)E * sizeof(int));

  float* h_out = (float*)d_out;             // n x 128 (h2)
  float* logits = h_out + (size_t)n * 128;  // n x 40

  const int ngemm = (n + 63) / 64;                       // 1563
  const int ncnt = (E + 256 * EPT - 1) / (256 * EPT);    // 782
  const int ngrp = max(ncnt, (ngemm + 1) / 2);           // 782
  const int nb = (nbins + 1023) / 1024;                  // 782 (<=1024)

  hipMemsetAsync(zeroed, 0, (size_t)(nbins + R_REP * n) * sizeof(int), stream);
  // count (atomic-bound, 8 edges/thread) || layer-0 gemm (VALU-bound), 1:2 mix
  fused_count_gemm<<<ngrp * 3, 256, 0, stream>>>(src, dst, cnt, dego, pos, x, W0, t0b,
                                                 n, E, ngemm, ncnt);
  norm_kernel<<<(n + 255) / 256, 256, 0, stream>>>(dego, c_src, n);
  scan_partial<<<nb, 256, 0, stream>>>(cnt, partials, nbins);
  scan_blocksums<<<1, 1024, 0, stream>>>(partials, nb);
  scan_final<<<nb, 256, 0, stream>>>(cnt, partials, row_start, nbins);
  fill_csr<<<(E + 255) / 256, 256, 0, stream>>>(src, dst, row_start, pos, csr, E);

  // h1b(bf16) = relu(agg(t0b * c_src[s]) * c_dst + b0)
  agg_kernel<true, true, true><<<(n + 3) / 4, 256, 0, stream>>>(
      t0b, row_start, csr, c_src, b0, (void*)h1b, n);
  // t1b(bf16) = (h1b @ W1) * c_src   (reuse t0b buffer)
  gemm128_bf16<<<(n + 63) / 64, 256, 0, stream>>>(h1b, W1, c_src, t0b, n);
  // h2(fp32, d_out) = agg(t1b) * c_dst + b1
  agg_kernel<false, false, false><<<(n + 3) / 4, 256, 0, stream>>>(
      t0b, row_start, csr, c_src, b1, (void*)h_out, n);
  // logits = relu(h2) @ Wc + bc
  logits_kernel<<<(n + 31) / 32, 256, 0, stream>>>(h_out, Wc, bc, logits, n);
}

// Round 2
// 618.801 us; speedup vs baseline: 1.1766x; 1.1766x over previous
//
#include <hip/hip_runtime.h>
#include <cstdint>
#include <cstddef>

// ---------------------------------------------------------------------------
// GCN forward on MI355X.
// R6: kill per-edge global atomics. R4/R5 showed the count role is capped at
//     ~267us regardless of schedule; WRITE_SIZE (206MB ~= 3.2M atomics x 64B)
//     says every random device-scope atomicAdd is a full-line RMW at the
//     coherence point (per-XCD L2s non-coherent). Replace count/scan/fill with
//     a bucketed counting sort (128 nodes/bucket): LDS histograms + LDS
//     returning atomics + sequential scatter. All heavy traffic becomes
//     sequential (~60MB) instead of ~500MB line-amplified RMW.
// ---------------------------------------------------------------------------

#define NPB 128        // nodes per bucket
#define BSHIFT 7
#define NBLK_E 256     // edge-pass blocks (hist & scatter must match)

static __device__ __forceinline__ float4 ld4(const float* p) { return *(const float4*)p; }

static __device__ __forceinline__ float bf2f(unsigned int u) {
  union { unsigned int i; float f; } x; x.i = u << 16; return x.f;
}
static __device__ __forceinline__ unsigned int f2bf(float f) {
  union { float f; unsigned int i; } x; x.f = f;
  unsigned int r = x.i + 0x7fff + ((x.i >> 16) & 1);  // RTN-even
  return r >> 16;
}

// ---- pass A: per-block bucket histograms (dst-key and src-key) ------------
__global__ __launch_bounds__(256) void bucket_hist(const int* __restrict__ src,
                                                   const int* __restrict__ dst,
                                                   int* __restrict__ bhD, int* __restrict__ bhS,
                                                   int E, int nbk, int ept) {
  __shared__ int hD[1024], hS[1024];
  int t = threadIdx.x;
  for (int i = t; i < nbk; i += 256) { hD[i] = 0; hS[i] = 0; }
  __syncthreads();
  int base = blockIdx.x * 256 * ept + t;
  for (int j = 0; j < ept; j++) {
    int e = base + j * 256;
    if (e < E) {
      atomicAdd(&hD[dst[e] >> BSHIFT], 1);
      atomicAdd(&hS[src[e] >> BSHIFT], 1);
    }
  }
  __syncthreads();
  for (int i = t; i < nbk; i += 256) {
    bhD[(size_t)blockIdx.x * nbk + i] = hD[i];
    bhS[(size_t)blockIdx.x * nbk + i] = hS[i];
  }
}

// ---- pass A2: per-bucket exclusive scan across the 256 edge-blocks --------
__global__ __launch_bounds__(256) void bucket_scan_blocks(int* __restrict__ bhD,
                                                          int* __restrict__ bhS,
                                                          int* __restrict__ totD,
                                                          int* __restrict__ totS, int nbk) {
  __shared__ int lds[256];
  int b = blockIdx.x, t = threadIdx.x;
  int v = bhD[(size_t)t * nbk + b];
  lds[t] = v;
  __syncthreads();
  for (int off = 1; off < 256; off <<= 1) {
    int u = (t >= off) ? lds[t - off] : 0;
    __syncthreads();
    lds[t] += u;
    __syncthreads();
  }
  bhD[(size_t)t * nbk + b] = lds[t] - v;  // exclusive within bucket
  if (t == 255) totD[b] = lds[255];
  __syncthreads();
  int w = bhS[(size_t)t * nbk + b];
  lds[t] = w;
  __syncthreads();
  for (int off = 1; off < 256; off <<= 1) {
    int u = (t >= off) ? lds[t - off] : 0;
    __syncthreads();
    lds[t] += u;
    __syncthreads();
  }
  bhS[(size_t)t * nbk + b] = lds[t] - w;
  if (t == 255) totS[b] = lds[255];
}

// ---- pass A3: exclusive scan over bucket totals (nbk <= 1024) -------------
__global__ __launch_bounds__(1024) void bucket_base(const int* __restrict__ totD,
                                                    const int* __restrict__ totS,
                                                    int* __restrict__ baseD,
                                                    int* __restrict__ baseS, int nbk) {
  __shared__ int lds[1024];
  int t = threadIdx.x;
  int v = (t < nbk) ? totD[t] : 0;
  lds[t] = v;
  __syncthreads();
  for (int off = 1; off < 1024; off <<= 1) {
    int u = (t >= off) ? lds[t - off] : 0;
    __syncthreads();
    lds[t] += u;
    __syncthreads();
  }
  if (t < nbk) baseD[t] = lds[t] - v;
  if (t == 1023) baseD[nbk] = lds[1023];
  __syncthreads();
  int w = (t < nbk) ? totS[t] : 0;
  lds[t] = w;
  __syncthreads();
  for (int off = 1; off < 1024; off <<= 1) {
    int u = (t >= off) ? lds[t - off] : 0;
    __syncthreads();
    lds[t] += u;
    __syncthreads();
  }
  if (t < nbk) baseS[t] = lds[t] - w;
  if (t == 1023) baseS[nbk] = lds[1023];
}

// ---- pass B: scatter edges into bucket segments (LDS cursors) -------------
// ebufD word: bits[23:17]=dst&127, bits[16:0]=src   (n < 2^17)
__global__ __launch_bounds__(256) void bucket_scatter(
    const int* __restrict__ src, const int* __restrict__ dst,
    const int* __restrict__ bhD, const int* __restrict__ bhS,
    const int* __restrict__ baseD, const int* __restrict__ baseS,
    unsigned int* __restrict__ ebufD, uint8_t* __restrict__ ebufS,
    int E, int nbk, int ept) {
  __shared__ int cD[1024], cS[1024];
  int k = blockIdx.x, t = threadIdx.x;
  for (int i = t; i < nbk; i += 256) {
    cD[i] = baseD[i] + bhD[(size_t)k * nbk + i];
    cS[i] = baseS[i] + bhS[(size_t)k * nbk + i];
  }
  __syncthreads();
  int base = k * 256 * ept + t;
  for (int j = 0; j < ept; j++) {
    int e = base + j * 256;
    if (e < E) {
      int s = src[e], d = dst[e];
      int pD = atomicAdd(&cD[d >> BSHIFT], 1);
      ebufD[pD] = ((unsigned int)(d & (NPB - 1)) << 17) | (unsigned int)s;
      int pS = atomicAdd(&cS[s >> BSHIFT], 1);
      ebufS[pS] = (uint8_t)(s & (NPB - 1));
    }
  }
}

// ---- pass C-D: per dst-bucket count + scan + CSR fill ---------------------
__global__ __launch_bounds__(256) void csr_build(const unsigned int* __restrict__ ebufD,
                                                 const int* __restrict__ baseD,
                                                 int* __restrict__ row_start,
                                                 int* __restrict__ csr, int n, int nbk) {
  __shared__ int cnt[NPB], sc[NPB], cur[NPB];
  int b = blockIdx.x, t = threadIdx.x;
  if (t < NPB) cnt[t] = 0;
  __syncthreads();
  int s0 = baseD[b], s1 = baseD[b + 1];
  for (int i = s0 + t; i < s1; i += 256) atomicAdd(&cnt[ebufD[i] >> 17], 1);
  __syncthreads();
  int c = (t < NPB) ? cnt[t] : 0;
  if (t < NPB) sc[t] = c;
  __syncthreads();
  for (int off = 1; off < NPB; off <<= 1) {
    int u = (t < NPB && t >= off) ? sc[t - off] : 0;
    __syncthreads();
    if (t < NPB) sc[t] += u;
    __syncthreads();
  }
  if (t < NPB) {
    int start = s0 + sc[t] - c;  // exclusive
    cur[t] = start;
    int node = b * NPB + t;
    if (node < n) row_start[node] = start;
  }
  if (b == 0 && t == 0) row_start[n] = baseD[nbk];
  __syncthreads();
  for (int i = s0 + t; i < s1; i += 256) {
    unsigned int w = ebufD[i];
    int p = atomicAdd(&cur[w >> 17], 1);
    csr[p] = (int)(w & 0x1FFFFu);
  }
}

// ---- pass C-S: per src-bucket out-degree -> c_src -------------------------
__global__ __launch_bounds__(256) void outdeg_norm(const uint8_t* __restrict__ ebufS,
                                                   const int* __restrict__ baseS,
                                                   float* __restrict__ c_src, int n) {
  __shared__ int cnt[NPB];
  int b = blockIdx.x, t = threadIdx.x;
  if (t < NPB) cnt[t] = 0;
  __syncthreads();
  int s0 = baseS[b], s1 = baseS[b + 1];
  for (int i = s0 + t; i < s1; i += 256) atomicAdd(&cnt[ebufS[i]], 1);
  __syncthreads();
  int node = b * NPB + t;
  if (t < NPB && node < n) c_src[node] = rsqrtf(fmaxf((float)cnt[t], 1.0f));
}

// ---- t0b[n,128](bf16) = x[n,256] @ W0[256,128]  (fp32 accum) --------------
__global__ __launch_bounds__(256) void gemm256(const float* __restrict__ x,
                                               const float* __restrict__ W0,
                                               ushort* __restrict__ t0b, int n) {
  __shared__ float As[64][36];
  __shared__ float Bs[32][128];
  int tid = threadIdx.x;
  int tx = tid & 15;
  int ty = tid >> 4;
  int row0 = blockIdx.x * 64;
  float acc[4][8];
#pragma unroll
  for (int i = 0; i < 4; i++)
#pragma unroll
    for (int j = 0; j < 8; j++) acc[i][j] = 0.0f;

  for (int kt = 0; kt < 256; kt += 32) {
#pragma unroll
    for (int l = 0; l < 2; l++) {
      int idx = tid + l * 256;
      int m = idx >> 3, q = idx & 7;
      int gr = row0 + m;
      float4 v = make_float4(0.f, 0.f, 0.f, 0.f);
      if (gr < n) v = ld4(&x[(size_t)gr * 256 + kt + q * 4]);
      *(float4*)&As[m][q * 4] = v;
    }
#pragma unroll
    for (int l = 0; l < 4; l++) {
      int idx = tid + l * 256;
      int kk = idx >> 5, q = idx & 31;
      *(float4*)&Bs[kk][q * 4] = ld4(&W0[(size_t)(kt + kk) * 128 + q * 4]);
    }
    __syncthreads();
#pragma unroll
    for (int k = 0; k < 32; k++) {
      float a[4];
#pragma unroll
      for (int i = 0; i < 4; i++) a[i] = As[ty * 4 + i][k];
      float4 b0 = *(float4*)&Bs[k][tx * 8];
      float4 b1 = *(float4*)&Bs[k][tx * 8 + 4];
      float bb[8] = {b0.x, b0.y, b0.z, b0.w, b1.x, b1.y, b1.z, b1.w};
#pragma unroll
      for (int i = 0; i < 4; i++)
#pragma unroll
        for (int j = 0; j < 8; j++) acc[i][j] = fmaf(a[i], bb[j], acc[i][j]);
    }
    __syncthreads();
  }
#pragma unroll
  for (int i = 0; i < 4; i++) {
    int r = row0 + ty * 4 + i;
    if (r < n) {
      uint4 o;
      o.x = f2bf(acc[i][0]) | (f2bf(acc[i][1]) << 16);
      o.y = f2bf(acc[i][2]) | (f2bf(acc[i][3]) << 16);
      o.z = f2bf(acc[i][4]) | (f2bf(acc[i][5]) << 16);
      o.w = f2bf(acc[i][6]) | (f2bf(acc[i][7]) << 16);
      *(uint4*)&t0b[(size_t)r * 128 + tx * 8] = o;
    }
  }
}

// t1b[n,128](bf16) = (h1b[n,128](bf16) @ W1[128,128]) * c_src[n]  (fp32 accum)
__global__ __launch_bounds__(256) void gemm128_bf16(const ushort* __restrict__ A,
                                                    const float* __restrict__ W,
                                                    const float* __restrict__ c,
                                                    ushort* __restrict__ Y, int n) {
  __shared__ float As[64][36];
  __shared__ float Bs[32][128];
  int tid = threadIdx.x;
  int tx = tid & 15;
  int ty = tid >> 4;
  int row0 = blockIdx.x * 64;
  float acc[4][8];
#pragma unroll
  for (int i = 0; i < 4; i++)
#pragma unroll
    for (int j = 0; j < 8; j++) acc[i][j] = 0.0f;

  for (int kt = 0; kt < 128; kt += 32) {
    {  // stage A: 64 rows x 32 bf16 -> float; 8 elems/thread
      int m = tid >> 2, q = tid & 3;
      int gr = row0 + m;
      uint4 w = make_uint4(0u, 0u, 0u, 0u);
      if (gr < n) w = *(const uint4*)&A[(size_t)gr * 128 + kt + q * 8];
      float4 f0 = make_float4(bf2f(w.x & 0xffff), bf2f(w.x >> 16),
                              bf2f(w.y & 0xffff), bf2f(w.y >> 16));
      float4 f1 = make_float4(bf2f(w.z & 0xffff), bf2f(w.z >> 16),
                              bf2f(w.w & 0xffff), bf2f(w.w >> 16));
      *(float4*)&As[m][q * 8] = f0;
      *(float4*)&As[m][q * 8 + 4] = f1;
    }
#pragma unroll
    for (int l = 0; l < 4; l++) {
      int idx = tid + l * 256;
      int kk = idx >> 5, q = idx & 31;
      *(float4*)&Bs[kk][q * 4] = ld4(&W[(size_t)(kt + kk) * 128 + q * 4]);
    }
    __syncthreads();
#pragma unroll
    for (int k = 0; k < 32; k++) {
      float a[4];
#pragma unroll
      for (int i = 0; i < 4; i++) a[i] = As[ty * 4 + i][k];
      float4 b0 = *(float4*)&Bs[k][tx * 8];
      float4 b1 = *(float4*)&Bs[k][tx * 8 + 4];
      float bb[8] = {b0.x, b0.y, b0.z, b0.w, b1.x, b1.y, b1.z, b1.w};
#pragma unroll
      for (int i = 0; i < 4; i++)
#pragma unroll
        for (int j = 0; j < 8; j++) acc[i][j] = fmaf(a[i], bb[j], acc[i][j]);
    }
    __syncthreads();
  }
#pragma unroll
  for (int i = 0; i < 4; i++) {
    int r = row0 + ty * 4 + i;
    if (r < n) {
      float s = c[r];
      uint4 o;
      o.x = f2bf(acc[i][0] * s) | (f2bf(acc[i][1] * s) << 16);
      o.y = f2bf(acc[i][2] * s) | (f2bf(acc[i][3] * s) << 16);
      o.z = f2bf(acc[i][4] * s) | (f2bf(acc[i][5] * s) << 16);
      o.w = f2bf(acc[i][6] * s) | (f2bf(acc[i][7] * s) << 16);
      *(uint4*)&Y[(size_t)r * 128 + tx * 8] = o;
    }
  }
}

// One wave per dst node; lane holds 2 bf16 features (4B load per edge).
template <bool RELU, bool SCALE, bool OUT_BF16>
__global__ __launch_bounds__(256) void agg_kernel(const ushort* __restrict__ T,
                                                  const int* __restrict__ row_start,
                                                  const int* __restrict__ csr_src,
                                                  const float* __restrict__ c_src,
                                                  const float* __restrict__ bias,
                                                  void* __restrict__ out, int n) {
  int node = (blockIdx.x * 256 + threadIdx.x) >> 6;
  int lane = threadIdx.x & 63;
  if (node >= n) return;
  int e0 = row_start[node], e1 = row_start[node + 1];
  float ax = 0.f, ay = 0.f;
  int e = e0;
  for (; e + 1 < e1; e += 2) {  // 2-wide: two gathers in flight
    int s0 = csr_src[e], s1 = csr_src[e + 1];
    unsigned int w0 = *(const unsigned int*)&T[(size_t)s0 * 128 + lane * 2];
    unsigned int w1 = *(const unsigned int*)&T[(size_t)s1 * 128 + lane * 2];
    float fx0 = bf2f(w0 & 0xffff), fy0 = bf2f(w0 >> 16);
    float fx1 = bf2f(w1 & 0xffff), fy1 = bf2f(w1 >> 16);
    if (SCALE) {
      float cs0 = c_src[s0], cs1 = c_src[s1];
      fx0 *= cs0; fy0 *= cs0; fx1 *= cs1; fy1 *= cs1;
    }
    ax += fx0 + fx1;
    ay += fy0 + fy1;
  }
  if (e < e1) {
    int s0 = csr_src[e];
    unsigned int w0 = *(const unsigned int*)&T[(size_t)s0 * 128 + lane * 2];
    float fx0 = bf2f(w0 & 0xffff), fy0 = bf2f(w0 >> 16);
    if (SCALE) { float cs0 = c_src[s0]; fx0 *= cs0; fy0 *= cs0; }
    ax += fx0;
    ay += fy0;
  }
  float cd = rsqrtf(fmaxf((float)(e1 - e0), 1.0f));
  float rx = fmaf(ax, cd, bias[lane * 2]);
  float ry = fmaf(ay, cd, bias[lane * 2 + 1]);
  if (RELU) { rx = fmaxf(rx, 0.f); ry = fmaxf(ry, 0.f); }
  if (OUT_BF16) {
    ((unsigned int*)out)[(size_t)node * 64 + lane] = f2bf(rx) | (f2bf(ry) << 16);
  } else {
    float2 r2; r2.x = rx; r2.y = ry;
    ((float2*)out)[(size_t)node * 64 + lane] = r2;
  }
}

// logits[n,40] = relu(H[n,128]) @ Wc[128,40] + bc
__global__ __launch_bounds__(256) void logits_kernel(const float* __restrict__ H,
                                                     const float* __restrict__ Wc,
                                                     const float* __restrict__ bc,
                                                     float* __restrict__ out, int n) {
  __shared__ float Wl[128 * 40];
  for (int i = threadIdx.x; i < 128 * 40; i += 256) Wl[i] = Wc[i];
  __syncthreads();
  int rl = threadIdx.x >> 3;
  int cg = threadIdx.x & 7;
  int r = blockIdx.x * 32 + rl;
  if (r >= n) return;
  float acc[5] = {0.f, 0.f, 0.f, 0.f, 0.f};
  const float* hr = &H[(size_t)r * 128];
  for (int k = 0; k < 128; k++) {
    float v = fmaxf(hr[k], 0.f);
#pragma unroll
    for (int j = 0; j < 5; j++) acc[j] = fmaf(v, Wl[k * 40 + cg * 5 + j], acc[j]);
  }
#pragma unroll
  for (int j = 0; j < 5; j++) out[(size_t)r * 40 + cg * 5 + j] = acc[j] + bc[cg * 5 + j];
}

extern "C" void kernel_launch(void* const* d_in, const int* in_sizes, int n_in,
                              void* d_out, int out_size, void* d_ws, size_t ws_size,
                              hipStream_t stream) {
  const float* x = (const float*)d_in[0];
  const int* src = (const int*)d_in[1];
  const int* dst = (const int*)d_in[2];
  const float* W0 = (const float*)d_in[3];
  const float* b0 = (const float*)d_in[4];
  const float* W1 = (const float*)d_in[5];
  const float* b1 = (const float*)d_in[6];
  const float* Wc = (const float*)d_in[7];
  const float* bc = (const float*)d_in[8];
  const int n = in_sizes[0] / 256;
  const int E = in_sizes[1];
  const int nbk = (n + NPB - 1) >> BSHIFT;                 // 782 (<=1024)
  const int ept = (E + NBLK_E * 256 - 1) / (NBLK_E * 256); // 25

  char* wsp = (char*)d_ws;
  auto alloc = [&](size_t bytes) -> char* {
    char* p = wsp;
    wsp += (bytes + 255) & ~(size_t)255;
    return p;
  };
  ushort* t0b = (ushort*)alloc((size_t)n * 128 * sizeof(ushort));  // t0 / reused as t1
  ushort* h1b = (ushort*)alloc((size_t)n * 128 * sizeof(ushort));
  float* c_src = (float*)alloc((size_t)n * sizeof(float));
  int* bhD = (int*)alloc((size_t)NBLK_E * nbk * sizeof(int));
  int* bhS = (int*)alloc((size_t)NBLK_E * nbk * sizeof(int));
  int* totD = (int*)alloc((size_t)nbk * sizeof(int));
  int* totS = (int*)alloc((size_t)nbk * sizeof(int));
  int* baseD = (int*)alloc((size_t)(nbk + 1) * sizeof(int));
  int* baseS = (int*)alloc((size_t)(nbk + 1) * sizeof(int));
  unsigned int* ebufD = (unsigned int*)alloc((size_t)E * sizeof(unsigned int));
  uint8_t* ebufS = (uint8_t*)alloc((size_t)E);
  int* row_start = (int*)alloc((size_t)(n + 1) * sizeof(int));
  int* csr = (int*)alloc((size_t)E * sizeof(int));

  float* h_out = (float*)d_out;             // n x 128 (h2)
  float* logits = h_out + (size_t)n * 128;  // n x 40

  // layer-0 transform (independent of graph build)
  gemm256<<<(n + 63) / 64, 256, 0, stream>>>(x, W0, t0b, n);

  // atomic-free (global) CSR build: hist -> scans -> scatter -> per-bucket fill
  bucket_hist<<<NBLK_E, 256, 0, stream>>>(src, dst, bhD, bhS, E, nbk, ept);
  bucket_scan_blocks<<<nbk, 256, 0, stream>>>(bhD, bhS, totD, totS, nbk);
  bucket_base<<<1, 1024, 0, stream>>>(totD, totS, baseD, baseS, nbk);
  bucket_scatter<<<NBLK_E, 256, 0, stream>>>(src, dst, bhD, bhS, baseD, baseS,
                                             ebufD, ebufS, E, nbk, ept);
  csr_build<<<nbk, 256, 0, stream>>>(ebufD, baseD, row_start, csr, n, nbk);
  outdeg_norm<<<nbk, 256, 0, stream>>>(ebufS, baseS, c_src, n);

  // h1b(bf16) = relu(agg(t0b * c_src[s]) * c_dst + b0)
  agg_kernel<true, true, true><<<(n + 3) / 4, 256, 0, stream>>>(
      t0b, row_start, csr, c_src, b0, (void*)h1b, n);
  // t1b(bf16) = (h1b @ W1) * c_src   (reuse t0b buffer)
  gemm128_bf16<<<(n + 63) / 64, 256, 0, stream>>>(h1b, W1, c_src, t0b, n);
  // h2(fp32, d_out) = agg(t1b) * c_dst + b1
  agg_kernel<false, false, false><<<(n + 3) / 4, 256, 0, stream>>>(
      t0b, row_start, csr, c_src, b1, (void*)h_out, n);
  // logits = relu(h2) @ Wc + bc
  logits_kernel<<<(n + 31) / 32, 256, 0, stream>>>(h_out, Wc, bc, logits, n);
}

// Round 3
// 487.081 us; speedup vs baseline: 1.4947x; 1.2704x over previous
//
#include <hip/hip_runtime.h>
#include <cstdint>
#include <cstddef>

// ---------------------------------------------------------------------------
// GCN forward on MI355X.
// R7: both GEMMs on the matrix pipe. gemm256 was VALU-bound fp32 (130us,
//     52% VALUBusy, 41us FMA floor). Pipeline already rounds t0/t1 through
//     bf16, so bf16-input MFMA (fp32 accum) adds error of the same order.
//     16x16x32 bf16 MFMA, 64x128 tile, BK=64, XOR-swizzled LDS (16B granule
//     ^ row&7: row-major fragment reads are 16-way bank conflicts otherwise).
//     Weights pre-transposed+cast once (W0t/W1t) so B staging is coalesced.
//     c_src folded into gemm256 epilogue -> agg1 drops per-edge c_src loads;
//     aggs widened to 4 gathers in flight.
// ---------------------------------------------------------------------------

#define NPB 128        // nodes per bucket
#define BSHIFT 7
#define NBLK_E 256     // edge-pass blocks (hist & scatter must match)

typedef __attribute__((ext_vector_type(8))) short short8;
typedef __attribute__((ext_vector_type(4))) float f32x4;

static __device__ __forceinline__ float4 ld4(const float* p) { return *(const float4*)p; }

static __device__ __forceinline__ float bf2f(unsigned int u) {
  union { unsigned int i; float f; } x; x.i = u << 16; return x.f;
}
static __device__ __forceinline__ unsigned int f2bf(float f) {
  union { float f; unsigned int i; } x; x.f = f;
  unsigned int r = x.i + 0x7fff + ((x.i >> 16) & 1);  // RTN-even
  return r >> 16;
}

// ---- weight prep: W0t[n][k]=bf16(W0[k][n]) (128x256), W1t (128x128) -------
__global__ __launch_bounds__(256) void prep_weights(const float* __restrict__ W0,
                                                    const float* __restrict__ W1,
                                                    ushort* __restrict__ W0t,
                                                    ushort* __restrict__ W1t) {
  int t = blockIdx.x * 256 + threadIdx.x;
  if (t < 128 * 256) {
    int nn = t >> 8, kk = t & 255;
    W0t[nn * 256 + kk] = (ushort)f2bf(W0[kk * 128 + nn]);
  }
  if (t < 128 * 128) {
    int nn = t >> 7, kk = t & 127;
    W1t[nn * 128 + kk] = (ushort)f2bf(W1[kk * 128 + nn]);
  }
}

// ---- pass A: per-block bucket histograms (dst-key and src-key) ------------
__global__ __launch_bounds__(256) void bucket_hist(const int* __restrict__ src,
                                                   const int* __restrict__ dst,
                                                   int* __restrict__ bhD, int* __restrict__ bhS,
                                                   int E, int nbk, int ept) {
  __shared__ int hD[1024], hS[1024];
  int t = threadIdx.x;
  for (int i = t; i < nbk; i += 256) { hD[i] = 0; hS[i] = 0; }
  __syncthreads();
  int base = blockIdx.x * 256 * ept + t;
  for (int j = 0; j < ept; j++) {
    int e = base + j * 256;
    if (e < E) {
      atomicAdd(&hD[dst[e] >> BSHIFT], 1);
      atomicAdd(&hS[src[e] >> BSHIFT], 1);
    }
  }
  __syncthreads();
  for (int i = t; i < nbk; i += 256) {
    bhD[(size_t)blockIdx.x * nbk + i] = hD[i];
    bhS[(size_t)blockIdx.x * nbk + i] = hS[i];
  }
}

// ---- pass A2: per-bucket exclusive scan across the 256 edge-blocks --------
__global__ __launch_bounds__(256) void bucket_scan_blocks(int* __restrict__ bhD,
                                                          int* __restrict__ bhS,
                                                          int* __restrict__ totD,
                                                          int* __restrict__ totS, int nbk) {
  __shared__ int lds[256];
  int b = blockIdx.x, t = threadIdx.x;
  int v = bhD[(size_t)t * nbk + b];
  lds[t] = v;
  __syncthreads();
  for (int off = 1; off < 256; off <<= 1) {
    int u = (t >= off) ? lds[t - off] : 0;
    __syncthreads();
    lds[t] += u;
    __syncthreads();
  }
  bhD[(size_t)t * nbk + b] = lds[t] - v;  // exclusive within bucket
  if (t == 255) totD[b] = lds[255];
  __syncthreads();
  int w = bhS[(size_t)t * nbk + b];
  lds[t] = w;
  __syncthreads();
  for (int off = 1; off < 256; off <<= 1) {
    int u = (t >= off) ? lds[t - off] : 0;
    __syncthreads();
    lds[t] += u;
    __syncthreads();
  }
  bhS[(size_t)t * nbk + b] = lds[t] - w;
  if (t == 255) totS[b] = lds[255];
}

// ---- pass A3: exclusive scan over bucket totals (nbk <= 1024) -------------
__global__ __launch_bounds__(1024) void bucket_base(const int* __restrict__ totD,
                                                    const int* __restrict__ totS,
                                                    int* __restrict__ baseD,
                                                    int* __restrict__ baseS, int nbk) {
  __shared__ int lds[1024];
  int t = threadIdx.x;
  int v = (t < nbk) ? totD[t] : 0;
  lds[t] = v;
  __syncthreads();
  for (int off = 1; off < 1024; off <<= 1) {
    int u = (t >= off) ? lds[t - off] : 0;
    __syncthreads();
    lds[t] += u;
    __syncthreads();
  }
  if (t < nbk) baseD[t] = lds[t] - v;
  if (t == 1023) baseD[nbk] = lds[1023];
  __syncthreads();
  int w = (t < nbk) ? totS[t] : 0;
  lds[t] = w;
  __syncthreads();
  for (int off = 1; off < 1024; off <<= 1) {
    int u = (t >= off) ? lds[t - off] : 0;
    __syncthreads();
    lds[t] += u;
    __syncthreads();
  }
  if (t < nbk) baseS[t] = lds[t] - w;
  if (t == 1023) baseS[nbk] = lds[1023];
}

// ---- pass B: scatter edges into bucket segments (LDS cursors) -------------
// ebufD word: bits[23:17]=dst&127, bits[16:0]=src   (n < 2^17)
__global__ __launch_bounds__(256) void bucket_scatter(
    const int* __restrict__ src, const int* __restrict__ dst,
    const int* __restrict__ bhD, const int* __restrict__ bhS,
    const int* __restrict__ baseD, const int* __restrict__ baseS,
    unsigned int* __restrict__ ebufD, uint8_t* __restrict__ ebufS,
    int E, int nbk, int ept) {
  __shared__ int cD[1024], cS[1024];
  int k = blockIdx.x, t = threadIdx.x;
  for (int i = t; i < nbk; i += 256) {
    cD[i] = baseD[i] + bhD[(size_t)k * nbk + i];
    cS[i] = baseS[i] + bhS[(size_t)k * nbk + i];
  }
  __syncthreads();
  int base = k * 256 * ept + t;
  for (int j = 0; j < ept; j++) {
    int e = base + j * 256;
    if (e < E) {
      int s = src[e], d = dst[e];
      int pD = atomicAdd(&cD[d >> BSHIFT], 1);
      ebufD[pD] = ((unsigned int)(d & (NPB - 1)) << 17) | (unsigned int)s;
      int pS = atomicAdd(&cS[s >> BSHIFT], 1);
      ebufS[pS] = (uint8_t)(s & (NPB - 1));
    }
  }
}

// ---- pass C-D: per dst-bucket count + scan + CSR fill ---------------------
__global__ __launch_bounds__(256) void csr_build(const unsigned int* __restrict__ ebufD,
                                                 const int* __restrict__ baseD,
                                                 int* __restrict__ row_start,
                                                 int* __restrict__ csr, int n, int nbk) {
  __shared__ int cnt[NPB], sc[NPB], cur[NPB];
  int b = blockIdx.x, t = threadIdx.x;
  if (t < NPB) cnt[t] = 0;
  __syncthreads();
  int s0 = baseD[b], s1 = baseD[b + 1];
  for (int i = s0 + t; i < s1; i += 256) atomicAdd(&cnt[ebufD[i] >> 17], 1);
  __syncthreads();
  int c = (t < NPB) ? cnt[t] : 0;
  if (t < NPB) sc[t] = c;
  __syncthreads();
  for (int off = 1; off < NPB; off <<= 1) {
    int u = (t < NPB && t >= off) ? sc[t - off] : 0;
    __syncthreads();
    if (t < NPB) sc[t] += u;
    __syncthreads();
  }
  if (t < NPB) {
    int start = s0 + sc[t] - c;  // exclusive
    cur[t] = start;
    int node = b * NPB + t;
    if (node < n) row_start[node] = start;
  }
  if (b == 0 && t == 0) row_start[n] = baseD[nbk];
  __syncthreads();
  for (int i = s0 + t; i < s1; i += 256) {
    unsigned int w = ebufD[i];
    int p = atomicAdd(&cur[w >> 17], 1);
    csr[p] = (int)(w & 0x1FFFFu);
  }
}

// ---- pass C-S: per src-bucket out-degree -> c_src -------------------------
__global__ __launch_bounds__(256) void outdeg_norm(const uint8_t* __restrict__ ebufS,
                                                   const int* __restrict__ baseS,
                                                   float* __restrict__ c_src, int n) {
  __shared__ int cnt[NPB];
  int b = blockIdx.x, t = threadIdx.x;
  if (t < NPB) cnt[t] = 0;
  __syncthreads();
  int s0 = baseS[b], s1 = baseS[b + 1];
  for (int i = s0 + t; i < s1; i += 256) atomicAdd(&cnt[ebufS[i]], 1);
  __syncthreads();
  int node = b * NPB + t;
  if (t < NPB && node < n) c_src[node] = rsqrtf(fmaxf((float)cnt[t], 1.0f));
}

// ---------------------------------------------------------------------------
// MFMA GEMMs: 64x128 output tile, BK=64, 4 waves; wave w owns rows w*16..+16.
// LDS 16B-chunk XOR swizzle: phys_chunk = chunk ^ (row & 7).
// A frag: lane l -> A[l%16][(l/16)*8+j]; B via transposed store Bs[col][k];
// D: reg r -> D[(l/16)*4+r][l%16]   (m89-verified mapping).
// ---------------------------------------------------------------------------

// t0b[n,128](bf16) = (x[n,256] @ W0) * c_src[row]   (fp32 accum via MFMA)
__global__ __launch_bounds__(256) void gemm256_mfma(const float* __restrict__ x,
                                                    const ushort* __restrict__ W0t,
                                                    const float* __restrict__ c_src,
                                                    ushort* __restrict__ t0b, int n) {
  __shared__ alignas(16) ushort As[64 * 64];    // 8 KB
  __shared__ alignas(16) ushort Bs[128 * 64];   // 16 KB
  int tid = threadIdx.x;
  int row0 = blockIdx.x * 64;
  int lane = tid & 63;
  int w = tid >> 6;
  int l16 = lane & 15, hi = lane >> 4;
  f32x4 acc[8];
#pragma unroll
  for (int c = 0; c < 8; c++) acc[c] = (f32x4){0.f, 0.f, 0.f, 0.f};

  for (int kt = 0; kt < 256; kt += 64) {
    {  // stage A: row r=tid>>2, two 16B chunks; 8 fp32 -> 8 bf16 each
      int r = tid >> 2;
      int gr = row0 + r;
#pragma unroll
      for (int u = 0; u < 2; u++) {
        int c8 = (tid & 3) * 2 + u;  // 0..7
        float4 v0 = make_float4(0.f, 0.f, 0.f, 0.f), v1 = v0;
        if (gr < n) {
          v0 = ld4(&x[(size_t)gr * 256 + kt + c8 * 8]);
          v1 = ld4(&x[(size_t)gr * 256 + kt + c8 * 8 + 4]);
        }
        uint4 o;
        o.x = f2bf(v0.x) | (f2bf(v0.y) << 16);
        o.y = f2bf(v0.z) | (f2bf(v0.w) << 16);
        o.z = f2bf(v1.x) | (f2bf(v1.y) << 16);
        o.w = f2bf(v1.z) | (f2bf(v1.w) << 16);
        *(uint4*)&As[r * 64 + (c8 ^ (r & 7)) * 8] = o;
      }
    }
    {  // stage B: row r=tid>>1 (0..127), four 16B chunks from W0t (bf16)
      int r = tid >> 1;
#pragma unroll
      for (int u = 0; u < 4; u++) {
        int c8 = (tid & 1) * 4 + u;  // 0..7
        uint4 o = *(const uint4*)&W0t[(size_t)r * 256 + kt + c8 * 8];
        *(uint4*)&Bs[r * 64 + (c8 ^ (r & 7)) * 8] = o;
      }
    }
    __syncthreads();
#pragma unroll
    for (int ks = 0; ks < 2; ks++) {
      int ar = w * 16 + l16;
      int ac = ks * 4 + hi;
      short8 a = *(const short8*)&As[ar * 64 + (ac ^ (ar & 7)) * 8];
#pragma unroll
      for (int c = 0; c < 8; c++) {
        int br = c * 16 + l16;
        short8 b = *(const short8*)&Bs[br * 64 + (ac ^ (br & 7)) * 8];
        acc[c] = __builtin_amdgcn_mfma_f32_16x16x32_bf16(a, b, acc[c], 0, 0, 0);
      }
    }
    __syncthreads();
  }
  // epilogue: scale rows by c_src, store bf16
  float cs[4];
#pragma unroll
  for (int r = 0; r < 4; r++) {
    int gm = row0 + w * 16 + hi * 4 + r;
    cs[r] = (gm < n) ? c_src[gm] : 0.f;
  }
#pragma unroll
  for (int c = 0; c < 8; c++)
#pragma unroll
    for (int r = 0; r < 4; r++) {
      int gm = row0 + w * 16 + hi * 4 + r;
      if (gm < n) t0b[(size_t)gm * 128 + c * 16 + l16] = (ushort)f2bf(acc[c][r] * cs[r]);
    }
}

// t1b[n,128](bf16) = (h1b[n,128](bf16) @ W1) * c_src[row]   (MFMA)
__global__ __launch_bounds__(256) void gemm128_mfma(const ushort* __restrict__ A,
                                                    const ushort* __restrict__ W1t,
                                                    const float* __restrict__ c_src,
                                                    ushort* __restrict__ Y, int n) {
  __shared__ alignas(16) ushort As[64 * 64];    // 8 KB
  __shared__ alignas(16) ushort Bs[128 * 64];   // 16 KB
  int tid = threadIdx.x;
  int row0 = blockIdx.x * 64;
  int lane = tid & 63;
  int w = tid >> 6;
  int l16 = lane & 15, hi = lane >> 4;
  f32x4 acc[8];
#pragma unroll
  for (int c = 0; c < 8; c++) acc[c] = (f32x4){0.f, 0.f, 0.f, 0.f};

  for (int kt = 0; kt < 128; kt += 64) {
    {  // stage A (already bf16): row r=tid>>2, two 16B chunks
      int r = tid >> 2;
      int gr = row0 + r;
#pragma unroll
      for (int u = 0; u < 2; u++) {
        int c8 = (tid & 3) * 2 + u;
        uint4 o = make_uint4(0u, 0u, 0u, 0u);
        if (gr < n) o = *(const uint4*)&A[(size_t)gr * 128 + kt + c8 * 8];
        *(uint4*)&As[r * 64 + (c8 ^ (r & 7)) * 8] = o;
      }
    }
    {  // stage B from W1t
      int r = tid >> 1;
#pragma unroll
      for (int u = 0; u < 4; u++) {
        int c8 = (tid & 1) * 4 + u;
        uint4 o = *(const uint4*)&W1t[(size_t)r * 128 + kt + c8 * 8];
        *(uint4*)&Bs[r * 64 + (c8 ^ (r & 7)) * 8] = o;
      }
    }
    __syncthreads();
#pragma unroll
    for (int ks = 0; ks < 2; ks++) {
      int ar = w * 16 + l16;
      int ac = ks * 4 + hi;
      short8 a = *(const short8*)&As[ar * 64 + (ac ^ (ar & 7)) * 8];
#pragma unroll
      for (int c = 0; c < 8; c++) {
        int br = c * 16 + l16;
        short8 b = *(const short8*)&Bs[br * 64 + (ac ^ (br & 7)) * 8];
        acc[c] = __builtin_amdgcn_mfma_f32_16x16x32_bf16(a, b, acc[c], 0, 0, 0);
      }
    }
    __syncthreads();
  }
  float cs[4];
#pragma unroll
  for (int r = 0; r < 4; r++) {
    int gm = row0 + w * 16 + hi * 4 + r;
    cs[r] = (gm < n) ? c_src[gm] : 0.f;
  }
#pragma unroll
  for (int c = 0; c < 8; c++)
#pragma unroll
    for (int r = 0; r < 4; r++) {
      int gm = row0 + w * 16 + hi * 4 + r;
      if (gm < n) Y[(size_t)gm * 128 + c * 16 + l16] = (ushort)f2bf(acc[c][r] * cs[r]);
    }
}

// One wave per dst node; lane holds 2 bf16 features (4B load per edge).
// T rows are pre-scaled by c_src; 4 gathers in flight.
template <bool RELU, bool OUT_BF16>
__global__ __launch_bounds__(256) void agg_kernel(const ushort* __restrict__ T,
                                                  const int* __restrict__ row_start,
                                                  const int* __restrict__ csr_src,
                                                  const float* __restrict__ bias,
                                                  void* __restrict__ out, int n) {
  int node = (blockIdx.x * 256 + threadIdx.x) >> 6;
  int lane = threadIdx.x & 63;
  if (node >= n) return;
  int e0 = row_start[node], e1 = row_start[node + 1];
  float ax = 0.f, ay = 0.f;
  int e = e0;
  for (; e + 3 < e1; e += 4) {
    int s0 = csr_src[e], s1 = csr_src[e + 1], s2 = csr_src[e + 2], s3 = csr_src[e + 3];
    unsigned int w0 = *(const unsigned int*)&T[(size_t)s0 * 128 + lane * 2];
    unsigned int w1 = *(const unsigned int*)&T[(size_t)s1 * 128 + lane * 2];
    unsigned int w2 = *(const unsigned int*)&T[(size_t)s2 * 128 + lane * 2];
    unsigned int w3 = *(const unsigned int*)&T[(size_t)s3 * 128 + lane * 2];
    ax += bf2f(w0 & 0xffff) + bf2f(w1 & 0xffff) + bf2f(w2 & 0xffff) + bf2f(w3 & 0xffff);
    ay += bf2f(w0 >> 16) + bf2f(w1 >> 16) + bf2f(w2 >> 16) + bf2f(w3 >> 16);
  }
  for (; e < e1; e++) {
    int s0 = csr_src[e];
    unsigned int w0 = *(const unsigned int*)&T[(size_t)s0 * 128 + lane * 2];
    ax += bf2f(w0 & 0xffff);
    ay += bf2f(w0 >> 16);
  }
  float cd = rsqrtf(fmaxf((float)(e1 - e0), 1.0f));
  float rx = fmaf(ax, cd, bias[lane * 2]);
  float ry = fmaf(ay, cd, bias[lane * 2 + 1]);
  if (RELU) { rx = fmaxf(rx, 0.f); ry = fmaxf(ry, 0.f); }
  if (OUT_BF16) {
    ((unsigned int*)out)[(size_t)node * 64 + lane] = f2bf(rx) | (f2bf(ry) << 16);
  } else {
    float2 r2; r2.x = rx; r2.y = ry;
    ((float2*)out)[(size_t)node * 64 + lane] = r2;
  }
}

// logits[n,40] = relu(H[n,128]) @ Wc[128,40] + bc
__global__ __launch_bounds__(256) void logits_kernel(const float* __restrict__ H,
                                                     const float* __restrict__ Wc,
                                                     const float* __restrict__ bc,
                                                     float* __restrict__ out, int n) {
  __shared__ float Wl[128 * 40];
  for (int i = threadIdx.x; i < 128 * 40; i += 256) Wl[i] = Wc[i];
  __syncthreads();
  int rl = threadIdx.x >> 3;
  int cg = threadIdx.x & 7;
  int r = blockIdx.x * 32 + rl;
  if (r >= n) return;
  float acc[5] = {0.f, 0.f, 0.f, 0.f, 0.f};
  const float* hr = &H[(size_t)r * 128];
  for (int k = 0; k < 128; k++) {
    float v = fmaxf(hr[k], 0.f);
#pragma unroll
    for (int j = 0; j < 5; j++) acc[j] = fmaf(v, Wl[k * 40 + cg * 5 + j], acc[j]);
  }
#pragma unroll
  for (int j = 0; j < 5; j++) out[(size_t)r * 40 + cg * 5 + j] = acc[j] + bc[cg * 5 + j];
}

extern "C" void kernel_launch(void* const* d_in, const int* in_sizes, int n_in,
                              void* d_out, int out_size, void* d_ws, size_t ws_size,
                              hipStream_t stream) {
  const float* x = (const float*)d_in[0];
  const int* src = (const int*)d_in[1];
  const int* dst = (const int*)d_in[2];
  const float* W0 = (const float*)d_in[3];
  const float* b0 = (const float*)d_in[4];
  const float* W1 = (const float*)d_in[5];
  const float* b1 = (const float*)d_in[6];
  const float* Wc = (const float*)d_in[7];
  const float* bc = (const float*)d_in[8];
  const int n = in_sizes[0] / 256;
  const int E = in_sizes[1];
  const int nbk = (n + NPB - 1) >> BSHIFT;                 // 782 (<=1024)
  const int ept = (E + NBLK_E * 256 - 1) / (NBLK_E * 256); // 25

  char* wsp = (char*)d_ws;
  auto alloc = [&](size_t bytes) -> char* {
    char* p = wsp;
    wsp += (bytes + 255) & ~(size_t)255;
    return p;
  };
  ushort* t0b = (ushort*)alloc((size_t)n * 128 * sizeof(ushort));  // t0 / reused as t1
  ushort* h1b = (ushort*)alloc((size_t)n * 128 * sizeof(ushort));
  float* c_src = (float*)alloc((size_t)n * sizeof(float));
  ushort* W0t = (ushort*)alloc((size_t)128 * 256 * sizeof(ushort));
  ushort* W1t = (ushort*)alloc((size_t)128 * 128 * sizeof(ushort));
  int* bhD = (int*)alloc((size_t)NBLK_E * nbk * sizeof(int));
  int* bhS = (int*)alloc((size_t)NBLK_E * nbk * sizeof(int));
  int* totD = (int*)alloc((size_t)nbk * sizeof(int));
  int* totS = (int*)alloc((size_t)nbk * sizeof(int));
  int* baseD = (int*)alloc((size_t)(nbk + 1) * sizeof(int));
  int* baseS = (int*)alloc((size_t)(nbk + 1) * sizeof(int));
  unsigned int* ebufD = (unsigned int*)alloc((size_t)E * sizeof(unsigned int));
  uint8_t* ebufS = (uint8_t*)alloc((size_t)E);
  int* row_start = (int*)alloc((size_t)(n + 1) * sizeof(int));
  int* csr = (int*)alloc((size_t)E * sizeof(int));

  float* h_out = (float*)d_out;             // n x 128 (h2)
  float* logits = h_out + (size_t)n * 128;  // n x 40

  // weight transpose+cast (tiny, one-off per launch)
  prep_weights<<<128, 256, 0, stream>>>(W0, W1, W0t, W1t);

  // atomic-free (global) CSR build: hist -> scans -> scatter -> per-bucket fill
  bucket_hist<<<NBLK_E, 256, 0, stream>>>(src, dst, bhD, bhS, E, nbk, ept);
  bucket_scan_blocks<<<nbk, 256, 0, stream>>>(bhD, bhS, totD, totS, nbk);
  bucket_base<<<1, 1024, 0, stream>>>(totD, totS, baseD, baseS, nbk);
  bucket_scatter<<<NBLK_E, 256, 0, stream>>>(src, dst, bhD, bhS, baseD, baseS,
                                             ebufD, ebufS, E, nbk, ept);
  csr_build<<<nbk, 256, 0, stream>>>(ebufD, baseD, row_start, csr, n, nbk);
  outdeg_norm<<<nbk, 256, 0, stream>>>(ebufS, baseS, c_src, n);

  // t0b(bf16) = (x @ W0) * c_src[row]   (MFMA; c_src folded -> agg is scale-free)
  gemm256_mfma<<<(n + 63) / 64, 256, 0, stream>>>(x, W0t, c_src, t0b, n);
  // h1b(bf16) = relu(agg(t0b) * c_dst + b0)
  agg_kernel<true, true><<<(n + 3) / 4, 256, 0, stream>>>(
      t0b, row_start, csr, b0, (void*)h1b, n);
  // t1b(bf16) = (h1b @ W1) * c_src   (reuse t0b buffer)
  gemm128_mfma<<<(n + 63) / 64, 256, 0, stream>>>(h1b, W1t, c_src, t0b, n);
  // h2(fp32, d_out) = agg(t1b) * c_dst + b1
  agg_kernel<false, false><<<(n + 3) / 4, 256, 0, stream>>>(
      t0b, row_start, csr, b1, (void*)h_out, n);
  // logits = relu(h2) @ Wc + bc
  logits_kernel<<<(n + 31) / 32, 256, 0, stream>>>(h_out, Wc, bc, logits, n);
}

// Round 4
// 460.948 us; speedup vs baseline: 1.5795x; 1.0567x over previous
//
#include <hip/hip_runtime.h>
#include <cstdint>
#include <cstddef>

// ---------------------------------------------------------------------------
// GCN forward on MI355X.
// R8: agg_kernel was serialized-latency-bound (75us, 39% HBM, 37% VALU,
//     0 conflicts): per 4 edges it paid csr-load latency THEN gather latency
//     (2 round trips / 4 edges), and blocks held only 4 nodes each.
//     Now: persistent waves (2048 blocks, grid-stride), wave cooperatively
//     loads 64 edge indices in ONE coalesced read, broadcasts via __shfl,
//     and issues gathers 8-deep. One csr latency per node instead of 4.
//     GEMMs (MFMA, R7) and bucketed CSR build (R6) unchanged.
// ---------------------------------------------------------------------------

#define NPB 128        // nodes per bucket
#define BSHIFT 7
#define NBLK_E 256     // edge-pass blocks (hist & scatter must match)

typedef __attribute__((ext_vector_type(8))) short short8;
typedef __attribute__((ext_vector_type(4))) float f32x4;

static __device__ __forceinline__ float4 ld4(const float* p) { return *(const float4*)p; }

static __device__ __forceinline__ float bf2f(unsigned int u) {
  union { unsigned int i; float f; } x; x.i = u << 16; return x.f;
}
static __device__ __forceinline__ unsigned int f2bf(float f) {
  union { float f; unsigned int i; } x; x.f = f;
  unsigned int r = x.i + 0x7fff + ((x.i >> 16) & 1);  // RTN-even
  return r >> 16;
}

// ---- weight prep: W0t[n][k]=bf16(W0[k][n]) (128x256), W1t (128x128) -------
__global__ __launch_bounds__(256) void prep_weights(const float* __restrict__ W0,
                                                    const float* __restrict__ W1,
                                                    ushort* __restrict__ W0t,
                                                    ushort* __restrict__ W1t) {
  int t = blockIdx.x * 256 + threadIdx.x;
  if (t < 128 * 256) {
    int nn = t >> 8, kk = t & 255;
    W0t[nn * 256 + kk] = (ushort)f2bf(W0[kk * 128 + nn]);
  }
  if (t < 128 * 128) {
    int nn = t >> 7, kk = t & 127;
    W1t[nn * 128 + kk] = (ushort)f2bf(W1[kk * 128 + nn]);
  }
}

// ---- pass A: per-block bucket histograms (dst-key and src-key) ------------
__global__ __launch_bounds__(256) void bucket_hist(const int* __restrict__ src,
                                                   const int* __restrict__ dst,
                                                   int* __restrict__ bhD, int* __restrict__ bhS,
                                                   int E, int nbk, int ept) {
  __shared__ int hD[1024], hS[1024];
  int t = threadIdx.x;
  for (int i = t; i < nbk; i += 256) { hD[i] = 0; hS[i] = 0; }
  __syncthreads();
  int base = blockIdx.x * 256 * ept + t;
  for (int j = 0; j < ept; j++) {
    int e = base + j * 256;
    if (e < E) {
      atomicAdd(&hD[dst[e] >> BSHIFT], 1);
      atomicAdd(&hS[src[e] >> BSHIFT], 1);
    }
  }
  __syncthreads();
  for (int i = t; i < nbk; i += 256) {
    bhD[(size_t)blockIdx.x * nbk + i] = hD[i];
    bhS[(size_t)blockIdx.x * nbk + i] = hS[i];
  }
}

// ---- pass A2: per-bucket exclusive scan across the 256 edge-blocks --------
__global__ __launch_bounds__(256) void bucket_scan_blocks(int* __restrict__ bhD,
                                                          int* __restrict__ bhS,
                                                          int* __restrict__ totD,
                                                          int* __restrict__ totS, int nbk) {
  __shared__ int lds[256];
  int b = blockIdx.x, t = threadIdx.x;
  int v = bhD[(size_t)t * nbk + b];
  lds[t] = v;
  __syncthreads();
  for (int off = 1; off < 256; off <<= 1) {
    int u = (t >= off) ? lds[t - off] : 0;
    __syncthreads();
    lds[t] += u;
    __syncthreads();
  }
  bhD[(size_t)t * nbk + b] = lds[t] - v;  // exclusive within bucket
  if (t == 255) totD[b] = lds[255];
  __syncthreads();
  int w = bhS[(size_t)t * nbk + b];
  lds[t] = w;
  __syncthreads();
  for (int off = 1; off < 256; off <<= 1) {
    int u = (t >= off) ? lds[t - off] : 0;
    __syncthreads();
    lds[t] += u;
    __syncthreads();
  }
  bhS[(size_t)t * nbk + b] = lds[t] - w;
  if (t == 255) totS[b] = lds[255];
}

// ---- pass A3: exclusive scan over bucket totals (nbk <= 1024) -------------
__global__ __launch_bounds__(1024) void bucket_base(const int* __restrict__ totD,
                                                    const int* __restrict__ totS,
                                                    int* __restrict__ baseD,
                                                    int* __restrict__ baseS, int nbk) {
  __shared__ int lds[1024];
  int t = threadIdx.x;
  int v = (t < nbk) ? totD[t] : 0;
  lds[t] = v;
  __syncthreads();
  for (int off = 1; off < 1024; off <<= 1) {
    int u = (t >= off) ? lds[t - off] : 0;
    __syncthreads();
    lds[t] += u;
    __syncthreads();
  }
  if (t < nbk) baseD[t] = lds[t] - v;
  if (t == 1023) baseD[nbk] = lds[1023];
  __syncthreads();
  int w = (t < nbk) ? totS[t] : 0;
  lds[t] = w;
  __syncthreads();
  for (int off = 1; off < 1024; off <<= 1) {
    int u = (t >= off) ? lds[t - off] : 0;
    __syncthreads();
    lds[t] += u;
    __syncthreads();
  }
  if (t < nbk) baseS[t] = lds[t] - w;
  if (t == 1023) baseS[nbk] = lds[1023];
}

// ---- pass B: scatter edges into bucket segments (LDS cursors) -------------
// ebufD word: bits[23:17]=dst&127, bits[16:0]=src   (n < 2^17)
__global__ __launch_bounds__(256) void bucket_scatter(
    const int* __restrict__ src, const int* __restrict__ dst,
    const int* __restrict__ bhD, const int* __restrict__ bhS,
    const int* __restrict__ baseD, const int* __restrict__ baseS,
    unsigned int* __restrict__ ebufD, uint8_t* __restrict__ ebufS,
    int E, int nbk, int ept) {
  __shared__ int cD[1024], cS[1024];
  int k = blockIdx.x, t = threadIdx.x;
  for (int i = t; i < nbk; i += 256) {
    cD[i] = baseD[i] + bhD[(size_t)k * nbk + i];
    cS[i] = baseS[i] + bhS[(size_t)k * nbk + i];
  }
  __syncthreads();
  int base = k * 256 * ept + t;
  for (int j = 0; j < ept; j++) {
    int e = base + j * 256;
    if (e < E) {
      int s = src[e], d = dst[e];
      int pD = atomicAdd(&cD[d >> BSHIFT], 1);
      ebufD[pD] = ((unsigned int)(d & (NPB - 1)) << 17) | (unsigned int)s;
      int pS = atomicAdd(&cS[s >> BSHIFT], 1);
      ebufS[pS] = (uint8_t)(s & (NPB - 1));
    }
  }
}

// ---- pass C-D: per dst-bucket count + scan + CSR fill ---------------------
__global__ __launch_bounds__(256) void csr_build(const unsigned int* __restrict__ ebufD,
                                                 const int* __restrict__ baseD,
                                                 int* __restrict__ row_start,
                                                 int* __restrict__ csr, int n, int nbk) {
  __shared__ int cnt[NPB], sc[NPB], cur[NPB];
  int b = blockIdx.x, t = threadIdx.x;
  if (t < NPB) cnt[t] = 0;
  __syncthreads();
  int s0 = baseD[b], s1 = baseD[b + 1];
  for (int i = s0 + t; i < s1; i += 256) atomicAdd(&cnt[ebufD[i] >> 17], 1);
  __syncthreads();
  int c = (t < NPB) ? cnt[t] : 0;
  if (t < NPB) sc[t] = c;
  __syncthreads();
  for (int off = 1; off < NPB; off <<= 1) {
    int u = (t < NPB && t >= off) ? sc[t - off] : 0;
    __syncthreads();
    if (t < NPB) sc[t] += u;
    __syncthreads();
  }
  if (t < NPB) {
    int start = s0 + sc[t] - c;  // exclusive
    cur[t] = start;
    int node = b * NPB + t;
    if (node < n) row_start[node] = start;
  }
  if (b == 0 && t == 0) row_start[n] = baseD[nbk];
  __syncthreads();
  for (int i = s0 + t; i < s1; i += 256) {
    unsigned int w = ebufD[i];
    int p = atomicAdd(&cur[w >> 17], 1);
    csr[p] = (int)(w & 0x1FFFFu);
  }
}

// ---- pass C-S: per src-bucket out-degree -> c_src -------------------------
__global__ __launch_bounds__(256) void outdeg_norm(const uint8_t* __restrict__ ebufS,
                                                   const int* __restrict__ baseS,
                                                   float* __restrict__ c_src, int n) {
  __shared__ int cnt[NPB];
  int b = blockIdx.x, t = threadIdx.x;
  if (t < NPB) cnt[t] = 0;
  __syncthreads();
  int s0 = baseS[b], s1 = baseS[b + 1];
  for (int i = s0 + t; i < s1; i += 256) atomicAdd(&cnt[ebufS[i]], 1);
  __syncthreads();
  int node = b * NPB + t;
  if (t < NPB && node < n) c_src[node] = rsqrtf(fmaxf((float)cnt[t], 1.0f));
}

// ---------------------------------------------------------------------------
// MFMA GEMMs: 64x128 output tile, BK=64, 4 waves; wave w owns rows w*16..+16.
// LDS 16B-chunk XOR swizzle: phys_chunk = chunk ^ (row & 7).
// ---------------------------------------------------------------------------

// t0b[n,128](bf16) = (x[n,256] @ W0) * c_src[row]   (fp32 accum via MFMA)
__global__ __launch_bounds__(256) void gemm256_mfma(const float* __restrict__ x,
                                                    const ushort* __restrict__ W0t,
                                                    const float* __restrict__ c_src,
                                                    ushort* __restrict__ t0b, int n) {
  __shared__ alignas(16) ushort As[64 * 64];    // 8 KB
  __shared__ alignas(16) ushort Bs[128 * 64];   // 16 KB
  int tid = threadIdx.x;
  int row0 = blockIdx.x * 64;
  int lane = tid & 63;
  int w = tid >> 6;
  int l16 = lane & 15, hi = lane >> 4;
  f32x4 acc[8];
#pragma unroll
  for (int c = 0; c < 8; c++) acc[c] = (f32x4){0.f, 0.f, 0.f, 0.f};

  for (int kt = 0; kt < 256; kt += 64) {
    {  // stage A: row r=tid>>2, two 16B chunks; 8 fp32 -> 8 bf16 each
      int r = tid >> 2;
      int gr = row0 + r;
#pragma unroll
      for (int u = 0; u < 2; u++) {
        int c8 = (tid & 3) * 2 + u;  // 0..7
        float4 v0 = make_float4(0.f, 0.f, 0.f, 0.f), v1 = v0;
        if (gr < n) {
          v0 = ld4(&x[(size_t)gr * 256 + kt + c8 * 8]);
          v1 = ld4(&x[(size_t)gr * 256 + kt + c8 * 8 + 4]);
        }
        uint4 o;
        o.x = f2bf(v0.x) | (f2bf(v0.y) << 16);
        o.y = f2bf(v0.z) | (f2bf(v0.w) << 16);
        o.z = f2bf(v1.x) | (f2bf(v1.y) << 16);
        o.w = f2bf(v1.z) | (f2bf(v1.w) << 16);
        *(uint4*)&As[r * 64 + (c8 ^ (r & 7)) * 8] = o;
      }
    }
    {  // stage B: row r=tid>>1 (0..127), four 16B chunks from W0t (bf16)
      int r = tid >> 1;
#pragma unroll
      for (int u = 0; u < 4; u++) {
        int c8 = (tid & 1) * 4 + u;  // 0..7
        uint4 o = *(const uint4*)&W0t[(size_t)r * 256 + kt + c8 * 8];
        *(uint4*)&Bs[r * 64 + (c8 ^ (r & 7)) * 8] = o;
      }
    }
    __syncthreads();
#pragma unroll
    for (int ks = 0; ks < 2; ks++) {
      int ar = w * 16 + l16;
      int ac = ks * 4 + hi;
      short8 a = *(const short8*)&As[ar * 64 + (ac ^ (ar & 7)) * 8];
#pragma unroll
      for (int c = 0; c < 8; c++) {
        int br = c * 16 + l16;
        short8 b = *(const short8*)&Bs[br * 64 + (ac ^ (br & 7)) * 8];
        acc[c] = __builtin_amdgcn_mfma_f32_16x16x32_bf16(a, b, acc[c], 0, 0, 0);
      }
    }
    __syncthreads();
  }
  // epilogue: scale rows by c_src, store bf16
  float cs[4];
#pragma unroll
  for (int r = 0; r < 4; r++) {
    int gm = row0 + w * 16 + hi * 4 + r;
    cs[r] = (gm < n) ? c_src[gm] : 0.f;
  }
#pragma unroll
  for (int c = 0; c < 8; c++)
#pragma unroll
    for (int r = 0; r < 4; r++) {
      int gm = row0 + w * 16 + hi * 4 + r;
      if (gm < n) t0b[(size_t)gm * 128 + c * 16 + l16] = (ushort)f2bf(acc[c][r] * cs[r]);
    }
}

// t1b[n,128](bf16) = (h1b[n,128](bf16) @ W1) * c_src[row]   (MFMA)
__global__ __launch_bounds__(256) void gemm128_mfma(const ushort* __restrict__ A,
                                                    const ushort* __restrict__ W1t,
                                                    const float* __restrict__ c_src,
                                                    ushort* __restrict__ Y, int n) {
  __shared__ alignas(16) ushort As[64 * 64];    // 8 KB
  __shared__ alignas(16) ushort Bs[128 * 64];   // 16 KB
  int tid = threadIdx.x;
  int row0 = blockIdx.x * 64;
  int lane = tid & 63;
  int w = tid >> 6;
  int l16 = lane & 15, hi = lane >> 4;
  f32x4 acc[8];
#pragma unroll
  for (int c = 0; c < 8; c++) acc[c] = (f32x4){0.f, 0.f, 0.f, 0.f};

  for (int kt = 0; kt < 128; kt += 64) {
    {  // stage A (already bf16): row r=tid>>2, two 16B chunks
      int r = tid >> 2;
      int gr = row0 + r;
#pragma unroll
      for (int u = 0; u < 2; u++) {
        int c8 = (tid & 3) * 2 + u;
        uint4 o = make_uint4(0u, 0u, 0u, 0u);
        if (gr < n) o = *(const uint4*)&A[(size_t)gr * 128 + kt + c8 * 8];
        *(uint4*)&As[r * 64 + (c8 ^ (r & 7)) * 8] = o;
      }
    }
    {  // stage B from W1t
      int r = tid >> 1;
#pragma unroll
      for (int u = 0; u < 4; u++) {
        int c8 = (tid & 1) * 4 + u;
        uint4 o = *(const uint4*)&W1t[(size_t)r * 128 + kt + c8 * 8];
        *(uint4*)&Bs[r * 64 + (c8 ^ (r & 7)) * 8] = o;
      }
    }
    __syncthreads();
#pragma unroll
    for (int ks = 0; ks < 2; ks++) {
      int ar = w * 16 + l16;
      int ac = ks * 4 + hi;
      short8 a = *(const short8*)&As[ar * 64 + (ac ^ (ar & 7)) * 8];
#pragma unroll
      for (int c = 0; c < 8; c++) {
        int br = c * 16 + l16;
        short8 b = *(const short8*)&Bs[br * 64 + (ac ^ (br & 7)) * 8];
        acc[c] = __builtin_amdgcn_mfma_f32_16x16x32_bf16(a, b, acc[c], 0, 0, 0);
      }
    }
    __syncthreads();
  }
  float cs[4];
#pragma unroll
  for (int r = 0; r < 4; r++) {
    int gm = row0 + w * 16 + hi * 4 + r;
    cs[r] = (gm < n) ? c_src[gm] : 0.f;
  }
#pragma unroll
  for (int c = 0; c < 8; c++)
#pragma unroll
    for (int r = 0; r < 4; r++) {
      int gm = row0 + w * 16 + hi * 4 + r;
      if (gm < n) Y[(size_t)gm * 128 + c * 16 + l16] = (ushort)f2bf(acc[c][r] * cs[r]);
    }
}

// ---------------------------------------------------------------------------
// Persistent-wave aggregation. One wave per dst node at a time, grid-stride.
// Wave cooperatively loads up to 64 edge indices in ONE coalesced read, then
// broadcasts each via __shfl (no per-edge vmem on the index path); row
// gathers issue 8-deep. T rows pre-scaled by c_src.
// ---------------------------------------------------------------------------
template <bool RELU, bool OUT_BF16>
__global__ __launch_bounds__(256) void agg_kernel(const ushort* __restrict__ T,
                                                  const int* __restrict__ row_start,
                                                  const int* __restrict__ csr_src,
                                                  const float* __restrict__ bias,
                                                  void* __restrict__ out, int n) {
  int lane = threadIdx.x & 63;
  int gw = (blockIdx.x * 256 + threadIdx.x) >> 6;
  int nw = gridDim.x * 4;
  float bx = bias[lane * 2], by = bias[lane * 2 + 1];
  for (int node = gw; node < n; node += nw) {
    int e0 = row_start[node], e1 = row_start[node + 1];
    float ax = 0.f, ay = 0.f;
    for (int eb = e0; eb < e1; eb += 64) {
      int rem = e1 - eb;
      int cnt = rem < 64 ? rem : 64;
      int msrc = (lane < rem) ? csr_src[eb + lane] : 0;
      int j = 0;
      for (; j + 7 < cnt; j += 8) {
        unsigned int w[8];
#pragma unroll
        for (int u = 0; u < 8; u++) {
          int s = __shfl(msrc, j + u);
          w[u] = *(const unsigned int*)&T[(size_t)s * 128 + lane * 2];
        }
#pragma unroll
        for (int u = 0; u < 8; u++) {
          ax += bf2f(w[u] & 0xffff);
          ay += bf2f(w[u] >> 16);
        }
      }
      for (; j + 1 < cnt; j += 2) {
        int s0 = __shfl(msrc, j), s1 = __shfl(msrc, j + 1);
        unsigned int w0 = *(const unsigned int*)&T[(size_t)s0 * 128 + lane * 2];
        unsigned int w1 = *(const unsigned int*)&T[(size_t)s1 * 128 + lane * 2];
        ax += bf2f(w0 & 0xffff) + bf2f(w1 & 0xffff);
        ay += bf2f(w0 >> 16) + bf2f(w1 >> 16);
      }
      if (j < cnt) {
        int s0 = __shfl(msrc, j);
        unsigned int w0 = *(const unsigned int*)&T[(size_t)s0 * 128 + lane * 2];
        ax += bf2f(w0 & 0xffff);
        ay += bf2f(w0 >> 16);
      }
    }
    float cd = rsqrtf(fmaxf((float)(e1 - e0), 1.0f));
    float rx = fmaf(ax, cd, bx);
    float ry = fmaf(ay, cd, by);
    if (RELU) { rx = fmaxf(rx, 0.f); ry = fmaxf(ry, 0.f); }
    if (OUT_BF16) {
      ((unsigned int*)out)[(size_t)node * 64 + lane] = f2bf(rx) | (f2bf(ry) << 16);
    } else {
      float2 r2; r2.x = rx; r2.y = ry;
      ((float2*)out)[(size_t)node * 64 + lane] = r2;
    }
  }
}

// logits[n,40] = relu(H[n,128]) @ Wc[128,40] + bc
__global__ __launch_bounds__(256) void logits_kernel(const float* __restrict__ H,
                                                     const float* __restrict__ Wc,
                                                     const float* __restrict__ bc,
                                                     float* __restrict__ out, int n) {
  __shared__ float Wl[128 * 40];
  for (int i = threadIdx.x; i < 128 * 40; i += 256) Wl[i] = Wc[i];
  __syncthreads();
  int rl = threadIdx.x >> 3;
  int cg = threadIdx.x & 7;
  int r = blockIdx.x * 32 + rl;
  if (r >= n) return;
  float acc[5] = {0.f, 0.f, 0.f, 0.f, 0.f};
  const float* hr = &H[(size_t)r * 128];
  for (int k = 0; k < 128; k++) {
    float v = fmaxf(hr[k], 0.f);
#pragma unroll
    for (int j = 0; j < 5; j++) acc[j] = fmaf(v, Wl[k * 40 + cg * 5 + j], acc[j]);
  }
#pragma unroll
  for (int j = 0; j < 5; j++) out[(size_t)r * 40 + cg * 5 + j] = acc[j] + bc[cg * 5 + j];
}

extern "C" void kernel_launch(void* const* d_in, const int* in_sizes, int n_in,
                              void* d_out, int out_size, void* d_ws, size_t ws_size,
                              hipStream_t stream) {
  const float* x = (const float*)d_in[0];
  const int* src = (const int*)d_in[1];
  const int* dst = (const int*)d_in[2];
  const float* W0 = (const float*)d_in[3];
  const float* b0 = (const float*)d_in[4];
  const float* W1 = (const float*)d_in[5];
  const float* b1 = (const float*)d_in[6];
  const float* Wc = (const float*)d_in[7];
  const float* bc = (const float*)d_in[8];
  const int n = in_sizes[0] / 256;
  const int E = in_sizes[1];
  const int nbk = (n + NPB - 1) >> BSHIFT;                 // 782 (<=1024)
  const int ept = (E + NBLK_E * 256 - 1) / (NBLK_E * 256); // 25

  char* wsp = (char*)d_ws;
  auto alloc = [&](size_t bytes) -> char* {
    char* p = wsp;
    wsp += (bytes + 255) & ~(size_t)255;
    return p;
  };
  ushort* t0b = (ushort*)alloc((size_t)n * 128 * sizeof(ushort));  // t0 / reused as t1
  ushort* h1b = (ushort*)alloc((size_t)n * 128 * sizeof(ushort));
  float* c_src = (float*)alloc((size_t)n * sizeof(float));
  ushort* W0t = (ushort*)alloc((size_t)128 * 256 * sizeof(ushort));
  ushort* W1t = (ushort*)alloc((size_t)128 * 128 * sizeof(ushort));
  int* bhD = (int*)alloc((size_t)NBLK_E * nbk * sizeof(int));
  int* bhS = (int*)alloc((size_t)NBLK_E * nbk * sizeof(int));
  int* totD = (int*)alloc((size_t)nbk * sizeof(int));
  int* totS = (int*)alloc((size_t)nbk * sizeof(int));
  int* baseD = (int*)alloc((size_t)(nbk + 1) * sizeof(int));
  int* baseS = (int*)alloc((size_t)(nbk + 1) * sizeof(int));
  unsigned int* ebufD = (unsigned int*)alloc((size_t)E * sizeof(unsigned int));
  uint8_t* ebufS = (uint8_t*)alloc((size_t)E);
  int* row_start = (int*)alloc((size_t)(n + 1) * sizeof(int));
  int* csr = (int*)alloc((size_t)E * sizeof(int));

  float* h_out = (float*)d_out;             // n x 128 (h2)
  float* logits = h_out + (size_t)n * 128;  // n x 40

  // weight transpose+cast (tiny, one-off per launch)
  prep_weights<<<128, 256, 0, stream>>>(W0, W1, W0t, W1t);

  // atomic-free (global) CSR build: hist -> scans -> scatter -> per-bucket fill
  bucket_hist<<<NBLK_E, 256, 0, stream>>>(src, dst, bhD, bhS, E, nbk, ept);
  bucket_scan_blocks<<<nbk, 256, 0, stream>>>(bhD, bhS, totD, totS, nbk);
  bucket_base<<<1, 1024, 0, stream>>>(totD, totS, baseD, baseS, nbk);
  bucket_scatter<<<NBLK_E, 256, 0, stream>>>(src, dst, bhD, bhS, baseD, baseS,
                                             ebufD, ebufS, E, nbk, ept);
  csr_build<<<nbk, 256, 0, stream>>>(ebufD, baseD, row_start, csr, n, nbk);
  outdeg_norm<<<nbk, 256, 0, stream>>>(ebufS, baseS, c_src, n);

  // t0b(bf16) = (x @ W0) * c_src[row]   (MFMA; c_src folded -> agg is scale-free)
  gemm256_mfma<<<(n + 63) / 64, 256, 0, stream>>>(x, W0t, c_src, t0b, n);
  // h1b(bf16) = relu(agg(t0b) * c_dst + b0)
  agg_kernel<true, true><<<2048, 256, 0, stream>>>(
      t0b, row_start, csr, b0, (void*)h1b, n);
  // t1b(bf16) = (h1b @ W1) * c_src   (reuse t0b buffer)
  gemm128_mfma<<<(n + 63) / 64, 256, 0, stream>>>(h1b, W1t, c_src, t0b, n);
  // h2(fp32, d_out) = agg(t1b) * c_dst + b1
  agg_kernel<false, false><<<2048, 256, 0, stream>>>(
      t0b, row_start, csr, b1, (void*)h_out, n);
  // logits = relu(h2) @ Wc + bc
  logits_kernel<<<(n + 31) / 32, 256, 0, stream>>>(h_out, Wc, bc, logits, n);
}